// Round 2
// baseline (341.363 us; speedup 1.0000x reference)
//
#include <hip/hip_runtime.h>
#include <cstdint>

typedef unsigned short u16;
typedef short bf16x8 __attribute__((ext_vector_type(8)));
typedef float f32x4 __attribute__((ext_vector_type(4)));
typedef float f32x16 __attribute__((ext_vector_type(16)));
typedef unsigned int u32x2 __attribute__((ext_vector_type(2)));
typedef unsigned int u32x4 __attribute__((ext_vector_type(4)));

#define NB 4
#define SEQ 2048
#define DMODEL 1024
#define NHEADS 16
#define DHEAD 64
#define BHTOT (NB*NHEADS)   // 64
#define MROWS (NB*SEQ)      // 8192

__device__ __forceinline__ float bf2f(u16 u){
  union { unsigned int i; float f; } x; x.i = ((unsigned int)u)<<16; return x.f;
}
__device__ __forceinline__ u16 f2bf(float f){
  union { float f; unsigned int i; } x; x.f = f;
  unsigned int r = x.i + 0x7fffu + ((x.i>>16)&1u);
  return (u16)(r>>16);
}

typedef const __attribute__((address_space(1))) unsigned int* gas_t;
typedef __attribute__((address_space(3))) unsigned int* las_t;
__device__ __forceinline__ void async_cp16(const void* g, void* l){
  __builtin_amdgcn_global_load_lds((gas_t)g, (las_t)l, 16, 0, 0);
}

// permlane32_swap: rows 32-63 of a exchange with rows 0-31 of b
__device__ __forceinline__ void plswap(unsigned int &a, unsigned int &b){
#if __has_builtin(__builtin_amdgcn_permlane32_swap)
  u32x2 r = __builtin_amdgcn_permlane32_swap(a, b, false, false);
  a = r[0]; b = r[1];
#else
  asm("v_permlane32_swap_b32 %0, %1" : "+v"(a), "+v"(b));
#endif
}

// ---------------- fp32 -> bf16 cast for BOTH weights (one launch) ----------------
__global__ __launch_bounds__(256) void cast2_kernel(const float* __restrict__ wa, u16* __restrict__ oa,
    const float* __restrict__ wb, u16* __restrict__ ob, int na4){
  int i = blockIdx.x*256 + threadIdx.x;
  const float* src; u16* dst; int j;
  if(i < na4){ src = wa; dst = oa; j = i; }
  else       { src = wb; dst = ob; j = i - na4; }
  float4 v = ((const float4*)src)[j];
  ushort4 o;
  o.x=f2bf(v.x); o.y=f2bf(v.y); o.z=f2bf(v.z); o.w=f2bf(v.w);
  ((ushort4*)dst)[j] = o;
}

// ---------------- LayerNorm: x fp32 -> h bf16 (f32 stats) ----------------
__global__ __launch_bounds__(256) void ln_kernel(const float* __restrict__ x, u16* __restrict__ h){
  int row = blockIdx.x;
  const float* xr = x + (size_t)row*DMODEL;
  u16* hr = h + (size_t)row*DMODEL;
  int t = threadIdx.x;
  float4 v = ((const float4*)xr)[t];
  float f0=v.x, f1=v.y, f2=v.z, f3=v.w;
  float s = f0+f1+f2+f3;
  float q = f0*f0+f1*f1+f2*f2+f3*f3;
  #pragma unroll
  for(int off=32; off; off>>=1){ s += __shfl_xor(s, off); q += __shfl_xor(q, off); }
  __shared__ float ss[4], sq[4];
  int wv = t>>6, lane = t&63;
  if(lane==0){ ss[wv]=s; sq[wv]=q; }
  __syncthreads();
  s = ss[0]+ss[1]+ss[2]+ss[3];
  q = sq[0]+sq[1]+sq[2]+sq[3];
  float mu  = s * (1.0f/DMODEL);
  float var = q * (1.0f/DMODEL) - mu*mu;
  float rs  = rsqrtf(var + 1e-8f);
  ushort4 o;
  o.x=f2bf((f0-mu)*rs); o.y=f2bf((f1-mu)*rs); o.z=f2bf((f2-mu)*rs); o.w=f2bf((f3-mu)*rs);
  ((ushort4*)hr)[t] = o;
}

// ---------------- GEMM: C[m,n] = sum_k A[m,k]*Bm[n,k], bf16 MFMA ----------------
#define BM 128
#define BN 128
#define BK 32

template<int MODE>
__global__ __launch_bounds__(256) void gemm_bt(const u16* __restrict__ A, const u16* __restrict__ Bm,
    u16* __restrict__ Qb, u16* __restrict__ Kb, u16* __restrict__ Vtb, float* __restrict__ outf,
    int M, int N, int K){
  __shared__ u16 As[BM*BK];
  __shared__ u16 Bs[BN*BK];
  int t = threadIdx.x;
  int lane = t&63, wv = t>>6;
  int c = lane&15, g = lane>>4;
  int wm = wv>>1, wn = wv&1;
  int m0 = blockIdx.y*BM, n0 = blockIdx.x*BN;
  f32x4 acc[4][4] = {};
  for(int k0=0;k0<K;k0+=BK){
    __syncthreads();
    #pragma unroll
    for(int i=0;i<2;i++){
      int e = t*8 + i*2048;
      int r = e>>5, col = e&31;
      async_cp16(&A [(size_t)(m0+r)*K + k0 + col], &As[e]);
      async_cp16(&Bm[(size_t)(n0+r)*K + k0 + col], &Bs[e]);
    }
    __syncthreads();
    bf16x8 af[4], bfr[4];
    #pragma unroll
    for(int i=0;i<4;i++){
      af[i]  = *(const bf16x8*)(&As[(wm*64 + i*16 + c)*BK + g*8]);
      bfr[i] = *(const bf16x8*)(&Bs[(wn*64 + i*16 + c)*BK + g*8]);
    }
    #pragma unroll
    for(int mi=0;mi<4;mi++)
      #pragma unroll
      for(int ni=0;ni<4;ni++)
        acc[mi][ni] = __builtin_amdgcn_mfma_f32_16x16x32_bf16(af[mi], bfr[ni], acc[mi][ni], 0,0,0);
  }
  if(MODE==1){
    #pragma unroll
    for(int mi=0;mi<4;mi++){
      int mrow = m0 + wm*64 + mi*16 + g*4;
      #pragma unroll
      for(int ni=0;ni<4;ni++){
        int ncol = n0 + wn*64 + ni*16 + c;
        #pragma unroll
        for(int r=0;r<4;r++)
          outf[(size_t)(mrow+r)*N + ncol] = acc[mi][ni][r];
      }
    }
  } else {
    #pragma unroll
    for(int ni=0;ni<4;ni++){
      int n = n0 + wn*64 + ni*16 + c;
      int sel = n>>10, head = (n>>6)&15, d = n&63;
      #pragma unroll
      for(int mi=0;mi<4;mi++){
        int m = m0 + wm*64 + mi*16 + g*4;
        int b = m>>11, l = m&(SEQ-1);
        if(sel<2){
          u16* dst = (sel==0?Qb:Kb) + ((size_t)((b*NHEADS+head)*SEQ + l))*DHEAD + d;
          #pragma unroll
          for(int r=0;r<4;r++) dst[(size_t)r*DHEAD] = f2bf(acc[mi][ni][r]);
        } else {
          ushort4 pk;
          pk.x=f2bf(acc[mi][ni][0]); pk.y=f2bf(acc[mi][ni][1]);
          pk.z=f2bf(acc[mi][ni][2]); pk.w=f2bf(acc[mi][ni][3]);
          *(ushort4*)(&Vtb[((size_t)((b*NHEADS+head)*DHEAD + d))*SEQ + l]) = pk;
        }
      }
    }
  }
}

// ---------------- RoPE: one thread per (l,j), sincos once, loop over bh ----------------
// Q additionally pre-scaled by scale*log2(e) so attn's softmax is a bare exp2.
#define SC2 0.180336879f   // 0.125 * log2(e)
__global__ __launch_bounds__(256) void rope_kernel(u16* __restrict__ Q, u16* __restrict__ Kb){
  int tid = blockIdx.x*256 + threadIdx.x;   // SEQ*32 threads
  int j = tid&31, l = tid>>5;
  float inv = exp2f(-(float)j * (13.28771237954945f/32.0f)); // 10000^(-j/32)
  float sn, cs;
  sincosf((float)l*inv, &sn, &cs);
  size_t base = (size_t)l*DHEAD + 2*j;
  #pragma unroll 4
  for(int bh=0; bh<BHTOT; bh++){
    size_t off = base + (size_t)bh*SEQ*DHEAD;
    ushort2 q2 = *(ushort2*)(&Q[off]);
    float x1=bf2f(q2.x), x2=bf2f(q2.y);
    ushort2 o;
    o.x = f2bf((x1*cs - x2*sn)*SC2); o.y = f2bf((x1*sn + x2*cs)*SC2);
    *(ushort2*)(&Q[off]) = o;
    ushort2 k2 = *(ushort2*)(&Kb[off]);
    x1=bf2f(k2.x); x2=bf2f(k2.y);
    o.x = f2bf(x1*cs - x2*sn); o.y = f2bf(x1*sn + x2*cs);
    *(ushort2*)(&Kb[off]) = o;
  }
}

// ---------------- Flash attention: 32x32 swapped-QK^T, in-register P ----------------
// Block = 128 threads (2 waves) owns one 32-row q strip s; causal range s+1 KV
// tiles split between the waves; exact add-merge (no online max; scores bounded,
// Q pre-scaled so P = exp2(S)).
// Per tile: S^T = mfma32x32x16(K, Q)  -> lane holds P[q=lane&31][k=(reg&3)+8*(reg>>2)+4*(lane>>5)]
// P -> bf16 PV A-frags entirely in registers: 8x v_cvt_pk_bf16_f32 + 4x permlane32_swap
// (T12). No P LDS round-trip; LDS only for the 2-wave merge epilogue.
#define OSTR 66   // Osum row stride (floats)

#define LOADK32(TILE, KF) { int tb_=(TILE)*32; \
  _Pragma("unroll") for(int dk_=0;dk_<4;dk_++) \
    KF[dk_] = *(const bf16x8*)(&Kp[(size_t)(tb_ + c32)*DHEAD + dk_*16 + h8]); }

#define LOADV32(TILE, VF) { int tb_=(TILE)*32; \
  _Pragma("unroll") for(int dt_=0;dt_<2;dt_++) \
    _Pragma("unroll") for(int ks_=0;ks_<2;ks_++) \
      VF[dt_][ks_] = *(const bf16x8*)(&Vp[(size_t)(dt_*32 + c32)*SEQ + tb_ + ks_*16 + h8]); }

#define QKS32(KF) { \
  f32x16 z_ = {}; \
  z_ = __builtin_amdgcn_mfma_f32_32x32x16_bf16(KF[0], qf[0], z_, 0,0,0); \
  z_ = __builtin_amdgcn_mfma_f32_32x32x16_bf16(KF[1], qf[1], z_, 0,0,0); \
  z_ = __builtin_amdgcn_mfma_f32_32x32x16_bf16(KF[2], qf[2], z_, 0,0,0); \
  z_ = __builtin_amdgcn_mfma_f32_32x32x16_bf16(KF[3], qf[3], z_, 0,0,0); \
  sc = z_; }

// pk_[j] = packed bf16 of P for regs (2j, 2j+1); after the two swaps per half,
// pk words are exactly the PV A-frag words (k = 8*(lane>>5)+elem).
#define EXPPACK(DIAG) { \
  unsigned int pk_[8]; \
  _Pragma("unroll") for(int j_=0;j_<8;j_++){ \
    float a_ = exp2f(sc[2*j_]); \
    float b_ = exp2f(sc[2*j_+1]); \
    if(DIAG){ \
      int k0_ = ((2*j_)&3)   + 8*((2*j_)>>2)   + 4*hl; \
      int k1_ = ((2*j_+1)&3) + 8*((2*j_+1)>>2) + 4*hl; \
      a_ = (k0_ <= c32) ? a_ : 0.f; \
      b_ = (k1_ <= c32) ? b_ : 0.f; } \
    asm("v_cvt_pk_bf16_f32 %0, %1, %2" : "=v"(pk_[j_]) : "v"(a_), "v"(b_)); } \
  plswap(pk_[0], pk_[2]); \
  plswap(pk_[1], pk_[3]); \
  plswap(pk_[4], pk_[6]); \
  plswap(pk_[5], pk_[7]); \
  u32x4 wa_ = { pk_[0], pk_[1], pk_[2], pk_[3] }; \
  u32x4 wb_ = { pk_[4], pk_[5], pk_[6], pk_[7] }; \
  pa0 = __builtin_bit_cast(bf16x8, wa_); \
  pa1 = __builtin_bit_cast(bf16x8, wb_); }

#define PVM32(VF) { \
  lacc  = __builtin_amdgcn_mfma_f32_32x32x16_bf16(pa0, ones, lacc, 0,0,0); \
  lacc  = __builtin_amdgcn_mfma_f32_32x32x16_bf16(pa1, ones, lacc, 0,0,0); \
  oacc0 = __builtin_amdgcn_mfma_f32_32x32x16_bf16(pa0, VF[0][0], oacc0, 0,0,0); \
  oacc0 = __builtin_amdgcn_mfma_f32_32x32x16_bf16(pa1, VF[0][1], oacc0, 0,0,0); \
  oacc1 = __builtin_amdgcn_mfma_f32_32x32x16_bf16(pa0, VF[1][0], oacc1, 0,0,0); \
  oacc1 = __builtin_amdgcn_mfma_f32_32x32x16_bf16(pa1, VF[1][1], oacc1, 0,0,0); }

__global__ __launch_bounds__(128) void attn_kernel(const u16* __restrict__ Q, const u16* __restrict__ Kb,
    const u16* __restrict__ Vt, u16* __restrict__ O){
  __shared__ float Osum[32*OSTR];
  __shared__ float Lsum[32];
  int t = threadIdx.x, lane = t&63, w = t>>6;
  int c32 = lane&31, hl = lane>>5, h8 = hl*8;
  int bh = blockIdx.x;
  int b = bh>>4, hh = bh&15;
  int s = 63 - blockIdx.y;       // long strips first
  int wrow = s*32;
  int nt = s+1;
  int h0 = (nt+1)>>1;
  int tbeg = w ? h0 : 0;
  int tend = w ? nt : h0;
  const u16* Qp = Q  + (size_t)bh*SEQ*DHEAD;
  const u16* Kp = Kb + (size_t)bh*SEQ*DHEAD;
  const u16* Vp = Vt + (size_t)bh*DHEAD*SEQ;
  bf16x8 ones;
  #pragma unroll
  for(int i=0;i<8;i++) ones[i] = (short)0x3f80;  // bf16 1.0

  // Q as B-frag: lane holds Q[wrow + (lane&31)][dk*16 + hl*8 .. +7]
  bf16x8 qf[4];
  #pragma unroll
  for(int dk=0;dk<4;dk++)
    qf[dk] = *(const bf16x8*)(&Qp[(size_t)(wrow + c32)*DHEAD + dk*16 + h8]);

  f32x16 oacc0 = {}, oacc1 = {}, lacc = {};
  f32x16 sc;
  bf16x8 kA[4], kB[4], vA[2][2], vB[2][2], pa0, pa1;

  int ntw = tend - tbeg;
  if(ntw > 0){
    LOADK32(tbeg, kA); LOADV32(tbeg, vA);
    int i = tbeg;
    #pragma unroll 1
    while(true){
      if(i+1 < tend){ LOADK32(i+1, kB); LOADV32(i+1, vB); }
      QKS32(kA);
      EXPPACK(i==s);
      PVM32(vA);
      i++;
      if(i >= tend) break;
      if(i+1 < tend){ LOADK32(i+1, kA); LOADV32(i+1, vA); }
      QKS32(kB);
      EXPPACK(i==s);
      PVM32(vB);
      i++;
      if(i >= tend) break;
    }
  }

  // exact merge of the two K-range partials (no max -> plain addition)
  // oacc row = (r&3)+8*(r>>2)+4*hl, col d = dt*32 + c32 ; lacc cols all equal rowsum.
  if(w==0){
    if(c32==0){
      #pragma unroll
      for(int r=0;r<16;r++) Lsum[(r&3)+8*(r>>2)+4*hl] = lacc[r];
    }
    #pragma unroll
    for(int r=0;r<16;r++){
      int row = (r&3)+8*(r>>2)+4*hl;
      Osum[row*OSTR + c32]      = oacc0[r];
      Osum[row*OSTR + 32 + c32] = oacc1[r];
    }
  }
  __syncthreads();
  if(w==1){
    #pragma unroll
    for(int r=0;r<16;r++){
      int row = (r&3)+8*(r>>2)+4*hl;
      float linv = 1.0f/(lacc[r] + Lsum[row]);
      float v0 = oacc0[r] + Osum[row*OSTR + c32];
      float v1 = oacc1[r] + Osum[row*OSTR + 32 + c32];
      size_t o = ((size_t)(b*SEQ + wrow + row))*DMODEL + hh*DHEAD;
      O[o + c32]      = f2bf(v0*linv);
      O[o + 32 + c32] = f2bf(v1*linv);
    }
  }
}

// ---------------- launch ----------------
extern "C" void kernel_launch(void* const* d_in, const int* in_sizes, int n_in,
                              void* d_out, int out_size, void* d_ws, size_t ws_size,
                              hipStream_t stream){
  const float* x    = (const float*)d_in[0];
  const float* W_in = (const float*)d_in[1];
  const float* W_o  = (const float*)d_in[2];
  u16* ws = (u16*)d_ws;
  const size_t T16 = (size_t)8*1024*1024;  // 8M bf16 elems = 16 MB per tensor
  u16* h   = ws;            // [8192][1024] bf16
  u16* Qb  = ws +   T16;    // [64][2048][64]
  u16* Kb  = ws + 2*T16;    // [64][2048][64]
  u16* Vtb = ws + 3*T16;    // [64][64][2048]  (V transposed)
  u16* Wb  = ws + 4*T16;    // W_in bf16 [3072][1024]
  u16* Wob = Wb + (size_t)3*DMODEL*DMODEL; // W_o bf16 [1024][1024]
  u16* Ob  = h;             // reuse: h dead after gemm1
  float* out = (float*)d_out;

  const int na4 = 3*DMODEL*DMODEL/4;  // W_in float4 count
  const int nb4 = DMODEL*DMODEL/4;
  cast2_kernel<<<dim3((na4+nb4)/256), dim3(256), 0, stream>>>(W_in, Wb, W_o, Wob, na4);
  ln_kernel<<<dim3(MROWS), dim3(256), 0, stream>>>(x, h);
  gemm_bt<0><<<dim3(3*DMODEL/BN, MROWS/BM), dim3(256), 0, stream>>>(
      h, Wb, Qb, Kb, Vtb, nullptr, MROWS, 3*DMODEL, DMODEL);
  rope_kernel<<<dim3(SEQ*32/256), dim3(256), 0, stream>>>(Qb, Kb);
  attn_kernel<<<dim3(BHTOT, 64), dim3(128), 0, stream>>>(Qb, Kb, Vtb, Ob);
  gemm_bt<1><<<dim3(DMODEL/BN, MROWS/BM), dim3(256), 0, stream>>>(
      Ob, Wob, nullptr, nullptr, nullptr, out, MROWS, DMODEL, DMODEL);
}